// Round 2
// baseline (230.574 us; speedup 1.0000x reference)
//
#include <hip/hip_runtime.h>

// Bottom-up HTMM on a complete 4-ary tree, depth 7 (t_size=21845).
// children(u) = 4u+1..4u+4 ; pos(u) = (u-1)&3 ; only labels t[u*7] are data.
// Decomposition: 256 independent subtrees rooted at level-4 nodes (85..340),
// 85 nodes each; plus the 85-node top (levels 0..3). 4 launches total.

#define G 16
#define C 8
#define GC 128           // G*C
#define TSIZE 21845
#define SL 5461          // first leaf

__device__ __forceinline__ float grp8_sum(float v) {
  v += __shfl_xor(v, 1);
  v += __shfl_xor(v, 2);
  v += __shfl_xor(v, 4);
  return v;
}

// ---------------- setup: softmaxes + logs + zero out ----------------
__global__ void setup_kernel(const float* __restrict__ ain, const float* __restrict__ bin,
                             const float* __restrict__ piin, const float* __restrict__ spin,
                             float* __restrict__ a_sp, float* __restrict__ log_a,
                             float* __restrict__ sm_b, float* __restrict__ log_b,
                             float* __restrict__ sm_pi, float* __restrict__ log_pi,
                             float* __restrict__ log_sp, float* __restrict__ out) {
  int blk = blockIdx.x, tid = threadIdx.x;
  if (blk < 16) {
    // softmax over labels (M=256) for b[g][c][:]
    int g = blk;
    __shared__ float red4[4];
    for (int c = 0; c < 8; ++c) {
      int row = g * 8 + c;
      float x = bin[row * 256 + tid];
      float m = x;
      #pragma unroll
      for (int off2 = 32; off2; off2 >>= 1) m = fmaxf(m, __shfl_xor(m, off2));
      if ((tid & 63) == 0) red4[tid >> 6] = m;
      __syncthreads();
      m = fmaxf(fmaxf(red4[0], red4[1]), fmaxf(red4[2], red4[3]));
      __syncthreads();
      float e = expf(x - m);
      float ssum = e;
      #pragma unroll
      for (int off2 = 32; off2; off2 >>= 1) ssum += __shfl_xor(ssum, off2);
      if ((tid & 63) == 0) red4[tid >> 6] = ssum;
      __syncthreads();
      ssum = red4[0] + red4[1] + red4[2] + red4[3];
      __syncthreads();
      sm_b[row * 256 + tid] = e / ssum;
      log_b[row * 256 + tid] = (x - m) - logf(ssum);
    }
  } else if (blk == 16) {
    // softmax of a over i (axis=1), times sm_sp -> a_sp; also log(sm_a)
    for (int col = tid; col < 512; col += 256) {
      int g = col >> 5, j = (col >> 2) & 7, l = col & 3;
      float x[8], m = -1e30f;
      #pragma unroll
      for (int i = 0; i < 8; ++i) { x[i] = ain[g*256 + i*32 + j*4 + l]; m = fmaxf(m, x[i]); }
      float ssum = 0.f;
      #pragma unroll
      for (int i = 0; i < 8; ++i) ssum += expf(x[i] - m);
      float ls = logf(ssum);
      float y0 = spin[g*4+0], y1 = spin[g*4+1], y2 = spin[g*4+2], y3 = spin[g*4+3];
      float ms = fmaxf(fmaxf(y0, y1), fmaxf(y2, y3));
      float d = expf(y0-ms) + expf(y1-ms) + expf(y2-ms) + expf(y3-ms);
      float spv = expf(spin[g*4+l] - ms) / d;
      #pragma unroll
      for (int i = 0; i < 8; ++i) {
        int o2 = g*256 + i*32 + j*4 + l;
        float smv = expf(x[i] - m) / ssum;
        a_sp[o2]  = smv * spv;
        log_a[o2] = (x[i] - m) - ls;
      }
    }
  } else {
    if (tid < 64) {
      // softmax of pi over c (axis=1) for each (g,l)
      int g = tid >> 2, l = tid & 3;
      float x[8], m = -1e30f;
      #pragma unroll
      for (int c = 0; c < 8; ++c) { x[c] = piin[g*32 + c*4 + l]; m = fmaxf(m, x[c]); }
      float ssum = 0.f;
      #pragma unroll
      for (int c = 0; c < 8; ++c) ssum += expf(x[c] - m);
      float ls = logf(ssum);
      #pragma unroll
      for (int c = 0; c < 8; ++c) {
        int o2 = g*32 + c*4 + l;
        sm_pi[o2]  = expf(x[c] - m) / ssum;
        log_pi[o2] = (x[c] - m) - ls;
      }
    } else if (tid < 80) {
      // log softmax of sp over l
      int g = tid - 64;
      float y[4], m = -1e30f;
      #pragma unroll
      for (int l = 0; l < 4; ++l) { y[l] = spin[g*4 + l]; m = fmaxf(m, y[l]); }
      float ssum = 0.f;
      #pragma unroll
      for (int l = 0; l < 4; ++l) ssum += expf(y[l] - m);
      float ls = logf(ssum);
      #pragma unroll
      for (int l = 0; l < 4; ++l) log_sp[g*4 + l] = (y[l] - m) - ls;
    } else if (tid >= 128 && tid < 144) {
      out[tid - 128] = 0.0f;   // zero the float accumulator (poisoned 0xAA)
    }
  }
}

// ---------------- shared per-item bodies ----------------
__device__ __forceinline__ void up_node(int u, int g, int i,
    const float* __restrict__ a_sp, const float* __restrict__ sm_b,
    const int* __restrict__ t, float* __restrict__ prior,
    float* __restrict__ beta, float* __restrict__ numbeta,
    float* __restrict__ eps, bool isroot) {
  const float* asp = a_sp + g*256 + i*32;
  float up = 0.f, ub = 0.f;
  int ch0 = 4*u + 1;
  #pragma unroll
  for (int l = 0; l < 4; ++l) {
    const float* pch = prior + (size_t)(ch0 + l) * GC + g * C;
    const float* bch = beta  + (size_t)(ch0 + l) * GC + g * C;
    #pragma unroll
    for (int j = 0; j < 8; ++j) {
      float wv = asp[j*4 + l];
      up += wv * pch[j];
      ub += wv * bch[j];
    }
  }
  float emis = sm_b[g*2048 + i*256 + t[u*7]];
  float tmp = emis * ub;                  // emis * u_bil * u_prior
  float ssum = grp8_sum(tmp);
  size_t o = (size_t)u * GC + g * C + i;
  float ubeta = tmp / ssum;
  prior[o]   = up;
  beta[o]    = ubeta;
  numbeta[o] = ub;                        // = prior * beta_il
  if (isroot) eps[o] = ubeta;             // eps_i[root] = beta[root]
}

// Down-step for one internal node item (u,g,i=parent state). Writes children's
// eps, returns this thread's share of a_lh + sp_lh + b_lh(u).
__device__ __forceinline__ double down_node(int u, int g, int i,
    const float* __restrict__ a_sp, const float* __restrict__ log_a,
    const float* __restrict__ log_sp, const float* __restrict__ log_b,
    const int* __restrict__ t, const float* __restrict__ numbeta,
    const float* __restrict__ beta, float* __restrict__ eps) {
  size_t o = (size_t)u * GC + g * C + i;
  float e  = eps[o];
  float pe = e / numbeta[o];
  const float* aspgi = a_sp  + g*256 + i*32;
  const float* lagi  = log_a + g*256 + i*32;
  float local = 0.f;
  int ch0 = 4*u + 1;
  #pragma unroll
  for (int l = 0; l < 4; ++l) {
    const float* bch = beta + (size_t)(ch0 + l) * GC + g * C;
    float S = 0.f, A = 0.f;
    #pragma unroll
    for (int j = 0; j < 8; ++j) {
      float wv = aspgi[j*4 + l];
      float bj = bch[j];
      S += wv * bj;
      A += wv * lagi[j*4 + l] * bj;
    }
    float ce = pe * S;                          // eps[ch_l][g,i]
    eps[(size_t)(ch0 + l) * GC + g * C + i] = ce;
    local += pe * A + ce * log_sp[g*4 + l];     // a_lh + sp_lh shares
  }
  float term = e * log_b[g*2048 + i*256 + t[u*7]];  // b_lh share for u
  return (double)local + (double)term;
}

// ---------------- upward over one depth-3 subtree (block = level-4 root) ----
__global__ __launch_bounds__(512) void up_sub_kernel(
    const float* __restrict__ a_sp, const float* __restrict__ sm_b,
    const float* __restrict__ sm_pi, const int* __restrict__ t,
    float* __restrict__ prior, float* __restrict__ beta,
    float* __restrict__ numbeta) {
  int b = blockIdx.x, tid = threadIdx.x;
  // leaves: 64 nodes x 128 items = 8192
  for (int it = 0; it < 16; ++it) {
    int item = it*512 + tid;
    int i = item & 7, g = (item >> 3) & 15, k = item >> 7;
    int u = SL + b*64 + k;
    float pr = sm_pi[g*32 + i*4 + ((u - 1) & 3)];
    float em = sm_b[g*2048 + i*256 + t[u*7]];
    float bt = pr * em;
    float s = grp8_sum(bt);
    size_t o = (size_t)u * GC + g * C + i;
    prior[o] = pr;
    beta[o]  = bt / s;
  }
  __syncthreads();
  // level 6 within subtree: 16 nodes, 2048 items
  for (int it = 0; it < 4; ++it) {
    int item = it*512 + tid;
    up_node(1365 + b*16 + (item >> 7), (item >> 3) & 15, item & 7,
            a_sp, sm_b, t, prior, beta, numbeta, nullptr, false);
  }
  __syncthreads();
  // level 5: 4 nodes, 512 items
  up_node(341 + b*4 + (tid >> 7), (tid >> 3) & 15, tid & 7,
          a_sp, sm_b, t, prior, beta, numbeta, nullptr, false);
  __syncthreads();
  // level 4 (subtree root): 128 items
  if (tid < 128)
    up_node(85 + b, (tid >> 3) & 15, tid & 7,
            a_sp, sm_b, t, prior, beta, numbeta, nullptr, false);
}

// ---------------- top: levels 3..0 up, 0..3 down, + its partial -----------
__global__ __launch_bounds__(1024) void top_kernel(
    const float* __restrict__ a_sp, const float* __restrict__ log_a,
    const float* __restrict__ log_sp, const float* __restrict__ sm_b,
    const float* __restrict__ log_b, const int* __restrict__ t,
    float* __restrict__ prior, float* __restrict__ beta,
    float* __restrict__ numbeta, float* __restrict__ eps,
    float* __restrict__ out) {
  int tid = threadIdx.x;
  int i = tid & 7, g = (tid >> 3) & 15;
  // up level 3: 64 nodes, 8192 items
  for (int it = 0; it < 8; ++it) {
    int item = it*1024 + tid;
    up_node(21 + (item >> 7), g, i, a_sp, sm_b, t, prior, beta, numbeta, nullptr, false);
  }
  __syncthreads();
  // up level 2: 16 nodes
  for (int it = 0; it < 2; ++it) {
    int item = it*1024 + tid;
    up_node(5 + (item >> 7), g, i, a_sp, sm_b, t, prior, beta, numbeta, nullptr, false);
  }
  __syncthreads();
  // up level 1: 4 nodes
  if (tid < 512)
    up_node(1 + (tid >> 7), g, i, a_sp, sm_b, t, prior, beta, numbeta, nullptr, false);
  __syncthreads();
  // up level 0 (root) + eps init
  if (tid < 128)
    up_node(0, g, i, a_sp, sm_b, t, prior, beta, numbeta, eps, true);
  __syncthreads();

  double acc = 0.0;
  // down level 0
  if (tid < 128)
    acc += down_node(0, g, i, a_sp, log_a, log_sp, log_b, t, numbeta, beta, eps);
  __syncthreads();
  // down level 1
  if (tid < 512)
    acc += down_node(1 + (tid >> 7), g, i, a_sp, log_a, log_sp, log_b, t, numbeta, beta, eps);
  __syncthreads();
  // down level 2
  for (int it = 0; it < 2; ++it) {
    int item = it*1024 + tid;
    acc += down_node(5 + (item >> 7), g, i, a_sp, log_a, log_sp, log_b, t, numbeta, beta, eps);
  }
  __syncthreads();
  // down level 3 (writes eps for level-4 subtree roots)
  for (int it = 0; it < 8; ++it) {
    int item = it*1024 + tid;
    acc += down_node(21 + (item >> 7), g, i, a_sp, log_a, log_sp, log_b, t, numbeta, beta, eps);
  }
  // reduce over i (8 lanes) then block
  acc += __shfl_xor(acc, 1);
  acc += __shfl_xor(acc, 2);
  acc += __shfl_xor(acc, 4);
  __shared__ double sd[128];
  if ((tid & 7) == 0) sd[tid >> 3] = acc;
  __syncthreads();
  if (tid < 16) {
    double s = 0.0;
    for (int q = tid; q < 128; q += 16) s += sd[q];
    atomicAdd(&out[tid], (float)s);
  }
}

// ---------------- downward subtree + fused likelihood reduction -----------
__global__ __launch_bounds__(512) void down_sub_kernel(
    const float* __restrict__ a_sp, const float* __restrict__ log_a,
    const float* __restrict__ log_sp, const float* __restrict__ log_b,
    const float* __restrict__ log_pi, const int* __restrict__ t,
    const float* __restrict__ numbeta, const float* __restrict__ beta,
    float* __restrict__ eps, float* __restrict__ out) {
  int b = blockIdx.x, tid = threadIdx.x;
  int i = tid & 7, g = (tid >> 3) & 15;
  double acc = 0.0;
  // level 4 (subtree root)
  if (tid < 128)
    acc += down_node(85 + b, g, i, a_sp, log_a, log_sp, log_b, t, numbeta, beta, eps);
  __syncthreads();
  // level 5: 4 nodes
  acc += down_node(341 + b*4 + (tid >> 7), g, i, a_sp, log_a, log_sp, log_b, t, numbeta, beta, eps);
  __syncthreads();
  // level 6: 16 nodes
  for (int it = 0; it < 4; ++it) {
    int item = it*512 + tid;
    acc += down_node(1365 + b*16 + (item >> 7), g, i, a_sp, log_a, log_sp, log_b, t, numbeta, beta, eps);
  }
  __syncthreads();
  // leaves: b_lh + pi_lh, 64 nodes x 128 items
  for (int it = 0; it < 16; ++it) {
    int item = it*512 + tid;
    int k = item >> 7;
    int u = SL + b*64 + k;
    float e = eps[(size_t)u * GC + g * C + i];
    acc += (double)(e * (log_b[g*2048 + i*256 + t[u*7]] +
                         log_pi[g*32 + i*4 + ((u - 1) & 3)]));
  }
  // reduce over i then block, one atomicAdd per (block, g)
  acc += __shfl_xor(acc, 1);
  acc += __shfl_xor(acc, 2);
  acc += __shfl_xor(acc, 4);
  __shared__ double sd[64];
  if ((tid & 7) == 0) sd[tid >> 3] = acc;
  __syncthreads();
  if (tid < 16) {
    double s = 0.0;
    for (int q = tid; q < 64; q += 16) s += sd[q];
    atomicAdd(&out[tid], (float)s);
  }
}

extern "C" void kernel_launch(void* const* d_in, const int* in_sizes, int n_in,
                              void* d_out, int out_size, void* d_ws, size_t ws_size,
                              hipStream_t stream) {
  const int*   t  = (const int*)d_in[0];
  // d_in[1] = t_limits (unused; tree shape is compile-time constant)
  const float* a  = (const float*)d_in[2];
  const float* b  = (const float*)d_in[3];
  const float* pi = (const float*)d_in[4];
  const float* sp = (const float*)d_in[5];
  float* out = (float*)d_out;

  char* w = (char*)d_ws;
  size_t off = 0;
  auto carve = [&](size_t bytes) -> void* {
    void* p = w + off;
    off += (bytes + 255) & ~(size_t)255;
    return p;
  };
  float* a_sp    = (float*)carve((size_t)16*8*8*4*4);
  float* log_a   = (float*)carve((size_t)16*8*8*4*4);
  float* sm_b    = (float*)carve((size_t)16*8*256*4);
  float* log_b   = (float*)carve((size_t)16*8*256*4);
  float* sm_pi   = (float*)carve((size_t)16*8*4*4);
  float* log_pi  = (float*)carve((size_t)16*8*4*4);
  float* log_sp  = (float*)carve((size_t)16*4*4);
  float* prior   = (float*)carve((size_t)TSIZE*GC*4);
  float* beta    = (float*)carve((size_t)TSIZE*GC*4);
  float* eps     = (float*)carve((size_t)TSIZE*GC*4);
  float* numbeta = (float*)carve((size_t)SL*GC*4);

  setup_kernel<<<18, 256, 0, stream>>>(a, b, pi, sp, a_sp, log_a, sm_b, log_b,
                                       sm_pi, log_pi, log_sp, out);
  up_sub_kernel<<<256, 512, 0, stream>>>(a_sp, sm_b, sm_pi, t, prior, beta, numbeta);
  top_kernel<<<1, 1024, 0, stream>>>(a_sp, log_a, log_sp, sm_b, log_b, t,
                                     prior, beta, numbeta, eps, out);
  down_sub_kernel<<<256, 512, 0, stream>>>(a_sp, log_a, log_sp, log_b, log_pi, t,
                                           numbeta, beta, eps, out);
}

// Round 3
// 122.262 us; speedup vs baseline: 1.8859x; 1.8859x over previous
//
#include <hip/hip_runtime.h>

// Bottom-up HTMM on a complete 4-ary tree, depth 7 (t_size=21845).
// children(u)=4u+1..4u+4, pos(u)=(u-1)&3; only labels t[u*7] are data.
// Key algebra: prior cancels everywhere (numbeta = prior*beta_il is the only
// combination used), so the prior array is never computed.
// Layouts: state arrays [u*128 + g*8 + i]; gather tables transposed to
// [label][g*8+i] so wave-uniform labels give coalesced 256B reads.

#define G 16
#define C 8
#define GC 128           // G*C
#define TSIZE 21845
#define SL 5461          // first leaf

__device__ __forceinline__ float grp8_sum(float v) {
  v += __shfl_xor(v, 1);
  v += __shfl_xor(v, 2);
  v += __shfl_xor(v, 4);
  return v;
}

// ---------------- setup: softmaxes + logs (transposed tables) -------------
__global__ void setup_kernel(const float* __restrict__ ain, const float* __restrict__ bin,
                             const float* __restrict__ piin, const float* __restrict__ spin,
                             float* __restrict__ a_sp, float* __restrict__ log_a,
                             float* __restrict__ sm_bT, float* __restrict__ log_bT,
                             float* __restrict__ sm_piT, float* __restrict__ log_piT,
                             float* __restrict__ log_sp, float* __restrict__ out) {
  int blk = blockIdx.x, tid = threadIdx.x;
  if (blk < 16) {
    // softmax over labels (M=256) for b[g][c][:]; write transposed [lab][g*8+c]
    int g = blk;
    __shared__ float red4[4];
    for (int c = 0; c < 8; ++c) {
      int row = g * 8 + c;
      float x = bin[row * 256 + tid];
      float m = x;
      #pragma unroll
      for (int off2 = 32; off2; off2 >>= 1) m = fmaxf(m, __shfl_xor(m, off2));
      if ((tid & 63) == 0) red4[tid >> 6] = m;
      __syncthreads();
      m = fmaxf(fmaxf(red4[0], red4[1]), fmaxf(red4[2], red4[3]));
      __syncthreads();
      float e = expf(x - m);
      float ssum = e;
      #pragma unroll
      for (int off2 = 32; off2; off2 >>= 1) ssum += __shfl_xor(ssum, off2);
      if ((tid & 63) == 0) red4[tid >> 6] = ssum;
      __syncthreads();
      ssum = red4[0] + red4[1] + red4[2] + red4[3];
      __syncthreads();
      sm_bT[tid * GC + row]  = e / ssum;
      log_bT[tid * GC + row] = (x - m) - logf(ssum);
    }
  } else if (blk == 16) {
    // softmax of a over i (axis=1), times sm_sp -> a_sp; also log(sm_a)
    for (int col = tid; col < 512; col += 256) {
      int g = col >> 5, j = (col >> 2) & 7, l = col & 3;
      float x[8], m = -1e30f;
      #pragma unroll
      for (int i = 0; i < 8; ++i) { x[i] = ain[g*256 + i*32 + j*4 + l]; m = fmaxf(m, x[i]); }
      float ssum = 0.f;
      #pragma unroll
      for (int i = 0; i < 8; ++i) ssum += expf(x[i] - m);
      float ls = logf(ssum);
      float y0 = spin[g*4+0], y1 = spin[g*4+1], y2 = spin[g*4+2], y3 = spin[g*4+3];
      float ms = fmaxf(fmaxf(y0, y1), fmaxf(y2, y3));
      float d = expf(y0-ms) + expf(y1-ms) + expf(y2-ms) + expf(y3-ms);
      float spv = expf(spin[g*4+l] - ms) / d;
      #pragma unroll
      for (int i = 0; i < 8; ++i) {
        int o2 = g*256 + i*32 + j*4 + l;
        float smv = expf(x[i] - m) / ssum;
        a_sp[o2]  = smv * spv;
        log_a[o2] = (x[i] - m) - ls;
      }
    }
  } else {
    if (tid < 64) {
      // softmax of pi over c (axis=1) for each (g,l); transposed [l][g*8+c]
      int g = tid >> 2, l = tid & 3;
      float x[8], m = -1e30f;
      #pragma unroll
      for (int c = 0; c < 8; ++c) { x[c] = piin[g*32 + c*4 + l]; m = fmaxf(m, x[c]); }
      float ssum = 0.f;
      #pragma unroll
      for (int c = 0; c < 8; ++c) ssum += expf(x[c] - m);
      float ls = logf(ssum);
      #pragma unroll
      for (int c = 0; c < 8; ++c) {
        sm_piT[l*GC + g*8 + c]  = expf(x[c] - m) / ssum;
        log_piT[l*GC + g*8 + c] = (x[c] - m) - ls;
      }
    } else if (tid < 80) {
      // log softmax of sp over l
      int g = tid - 64;
      float y[4], m = -1e30f;
      #pragma unroll
      for (int l = 0; l < 4; ++l) { y[l] = spin[g*4 + l]; m = fmaxf(m, y[l]); }
      float ssum = 0.f;
      #pragma unroll
      for (int l = 0; l < 4; ++l) ssum += expf(y[l] - m);
      float ls = logf(ssum);
      #pragma unroll
      for (int l = 0; l < 4; ++l) log_sp[g*4 + l] = (y[l] - m) - ls;
    } else if (tid >= 128 && tid < 144) {
      out[tid - 128] = 0.0f;   // zero the accumulator (poisoned 0xAA)
    }
  }
}

// ---------------- per-item bodies (asp/aal live in registers) -------------
__device__ __forceinline__ void up_step(int u, int gi, const float* asp,
    const float* __restrict__ sm_bT, const int* __restrict__ t,
    float* __restrict__ beta, float* __restrict__ numbeta) {
  int ch0 = 4*u + 1;
  int g8 = gi & 0x78;                 // (g)*8
  float ub = 0.f;
  #pragma unroll
  for (int l = 0; l < 4; ++l) {
    const float4* bp = (const float4*)(beta + (size_t)(ch0 + l) * GC + g8);
    float4 b0 = bp[0], b1 = bp[1];
    ub += asp[l]*b0.x + asp[4+l]*b0.y + asp[8+l]*b0.z + asp[12+l]*b0.w
        + asp[16+l]*b1.x + asp[20+l]*b1.y + asp[24+l]*b1.z + asp[28+l]*b1.w;
  }
  float tmp = sm_bT[t[u*7] * GC + gi] * ub;   // emis * numbeta
  float s = grp8_sum(tmp);
  size_t o = (size_t)u * GC + gi;
  beta[o]    = tmp / s;
  numbeta[o] = ub;
}

__device__ __forceinline__ double down_step(int u, int gi, const float* asp,
    const float* aal, const float* lsp,
    const float* __restrict__ log_bT, const int* __restrict__ t,
    const float* __restrict__ numbeta, const float* __restrict__ beta,
    float* __restrict__ eps) {
  size_t o = (size_t)u * GC + gi;
  float e  = eps[o];
  float pe = e / numbeta[o];
  int ch0 = 4*u + 1;
  int g8 = gi & 0x78;
  float local = 0.f;
  #pragma unroll
  for (int l = 0; l < 4; ++l) {
    const float4* bp = (const float4*)(beta + (size_t)(ch0 + l) * GC + g8);
    float4 b0 = bp[0], b1 = bp[1];
    float S = asp[l]*b0.x + asp[4+l]*b0.y + asp[8+l]*b0.z + asp[12+l]*b0.w
            + asp[16+l]*b1.x + asp[20+l]*b1.y + asp[24+l]*b1.z + asp[28+l]*b1.w;
    float A = aal[l]*b0.x + aal[4+l]*b0.y + aal[8+l]*b0.z + aal[12+l]*b0.w
            + aal[16+l]*b1.x + aal[20+l]*b1.y + aal[24+l]*b1.z + aal[28+l]*b1.w;
    float ce = pe * S;                       // eps[ch_l][g,i]
    eps[(size_t)(ch0 + l) * GC + gi] = ce;
    local += pe*A + ce*lsp[l];               // a_lh + sp_lh shares
  }
  return (double)local + (double)(e * log_bT[t[u*7] * GC + gi]);  // + b_lh(u)
}

// ---------------- upward: 256 subtrees (levels 7..4) ----------------------
__global__ __launch_bounds__(512, 2) void up_kernel(
    const float* __restrict__ a_sp, const float* __restrict__ sm_bT,
    const float* __restrict__ sm_piT, const int* __restrict__ t,
    float* __restrict__ beta, float* __restrict__ numbeta) {
  int b = blockIdx.x, tid = threadIdx.x;
  int gi = tid & 127;
  float asp[32];
  {
    const float4* pa = (const float4*)(a_sp + (gi >> 3)*256 + (gi & 7)*32);
    #pragma unroll
    for (int q = 0; q < 8; ++q) {
      float4 v = pa[q];
      asp[q*4+0]=v.x; asp[q*4+1]=v.y; asp[q*4+2]=v.z; asp[q*4+3]=v.w;
    }
  }
  // leaves: 64 nodes
  for (int it = 0; it < 16; ++it) {
    int k = it*4 + (tid >> 7);
    int u = SL + b*64 + k;
    float bt = sm_piT[(k & 3) * GC + gi] * sm_bT[t[u*7] * GC + gi];
    float s = grp8_sum(bt);
    beta[(size_t)u * GC + gi] = bt / s;
  }
  __syncthreads();
  // level 6: 16 nodes
  for (int it = 0; it < 4; ++it)
    up_step(1365 + b*16 + it*4 + (tid >> 7), gi, asp, sm_bT, t, beta, numbeta);
  __syncthreads();
  // level 5: 4 nodes
  up_step(341 + b*4 + (tid >> 7), gi, asp, sm_bT, t, beta, numbeta);
  __syncthreads();
  // level 4 (subtree root)
  if (tid < 128) up_step(85 + b, gi, asp, sm_bT, t, beta, numbeta);
}

// ---------------- top: g-split, levels 3..0 up then 0..3 down -------------
__global__ __launch_bounds__(512, 2) void top_kernel(
    const float* __restrict__ a_sp, const float* __restrict__ log_a,
    const float* __restrict__ log_sp, const float* __restrict__ sm_bT,
    const float* __restrict__ log_bT, const int* __restrict__ t,
    float* __restrict__ beta, float* __restrict__ numbeta,
    float* __restrict__ eps, float* __restrict__ out) {
  int g = blockIdx.x, tid = threadIdx.x;
  int i = tid & 7, gi = g*8 + i, q = tid >> 3;
  float asp[32], aal[32], lsp[4];
  {
    const float4* pa = (const float4*)(a_sp + g*256 + i*32);
    const float4* pl = (const float4*)(log_a + g*256 + i*32);
    #pragma unroll
    for (int k = 0; k < 8; ++k) {
      float4 va = pa[k], vl = pl[k];
      asp[k*4+0]=va.x; asp[k*4+1]=va.y; asp[k*4+2]=va.z; asp[k*4+3]=va.w;
      aal[k*4+0]=va.x*vl.x; aal[k*4+1]=va.y*vl.y; aal[k*4+2]=va.z*vl.z; aal[k*4+3]=va.w*vl.w;
    }
    #pragma unroll
    for (int l = 0; l < 4; ++l) lsp[l] = log_sp[g*4 + l];
  }
  up_step(21 + q, gi, asp, sm_bT, t, beta, numbeta);        // level 3: 64 nodes
  __syncthreads();
  if (tid < 128) up_step(5 + q, gi, asp, sm_bT, t, beta, numbeta);   // level 2
  __syncthreads();
  if (tid < 32)  up_step(1 + q, gi, asp, sm_bT, t, beta, numbeta);   // level 1
  __syncthreads();
  if (tid < 8) {
    up_step(0, gi, asp, sm_bT, t, beta, numbeta);                    // root
    eps[gi] = beta[gi];                                              // eps root
  }
  __syncthreads();
  double acc = 0.0;
  if (tid < 8)   acc += down_step(0, gi, asp, aal, lsp, log_bT, t, numbeta, beta, eps);
  __syncthreads();
  if (tid < 32)  acc += down_step(1 + q, gi, asp, aal, lsp, log_bT, t, numbeta, beta, eps);
  __syncthreads();
  if (tid < 128) acc += down_step(5 + q, gi, asp, aal, lsp, log_bT, t, numbeta, beta, eps);
  __syncthreads();
  acc += down_step(21 + q, gi, asp, aal, lsp, log_bT, t, numbeta, beta, eps); // level 3
  // reduce over block -> one atomic per g
  acc += __shfl_xor(acc, 1);
  acc += __shfl_xor(acc, 2);
  acc += __shfl_xor(acc, 4);
  __shared__ double sd[64];
  if (i == 0) sd[tid >> 3] = acc;
  __syncthreads();
  if (tid == 0) {
    double s = 0.0;
    for (int k = 0; k < 64; ++k) s += sd[k];
    atomicAdd(&out[g], (float)s);
  }
}

// ---------------- downward: 256 subtrees + fused reduction ----------------
__global__ __launch_bounds__(512, 2) void down_kernel(
    const float* __restrict__ a_sp, const float* __restrict__ log_a,
    const float* __restrict__ log_sp, const float* __restrict__ log_bT,
    const float* __restrict__ log_piT, const int* __restrict__ t,
    const float* __restrict__ numbeta, const float* __restrict__ beta,
    float* __restrict__ eps, float* __restrict__ out) {
  int b = blockIdx.x, tid = threadIdx.x;
  int gi = tid & 127, g = gi >> 3, i = gi & 7;
  float asp[32], aal[32], lsp[4];
  {
    const float4* pa = (const float4*)(a_sp + g*256 + i*32);
    const float4* pl = (const float4*)(log_a + g*256 + i*32);
    #pragma unroll
    for (int k = 0; k < 8; ++k) {
      float4 va = pa[k], vl = pl[k];
      asp[k*4+0]=va.x; asp[k*4+1]=va.y; asp[k*4+2]=va.z; asp[k*4+3]=va.w;
      aal[k*4+0]=va.x*vl.x; aal[k*4+1]=va.y*vl.y; aal[k*4+2]=va.z*vl.z; aal[k*4+3]=va.w*vl.w;
    }
    #pragma unroll
    for (int l = 0; l < 4; ++l) lsp[l] = log_sp[g*4 + l];
  }
  double acc = 0.0;
  // level 4 (subtree root; eps written by top_kernel)
  if (tid < 128)
    acc += down_step(85 + b, gi, asp, aal, lsp, log_bT, t, numbeta, beta, eps);
  __syncthreads();
  // level 5: 4 nodes
  acc += down_step(341 + b*4 + (tid >> 7), gi, asp, aal, lsp, log_bT, t, numbeta, beta, eps);
  __syncthreads();
  // level 6: 16 nodes
  for (int it = 0; it < 4; ++it)
    acc += down_step(1365 + b*16 + it*4 + (tid >> 7), gi, asp, aal, lsp, log_bT, t,
                     numbeta, beta, eps);
  __syncthreads();
  // leaves: b_lh + pi_lh
  for (int it = 0; it < 16; ++it) {
    int k = it*4 + (tid >> 7);
    int u = SL + b*64 + k;
    float e = eps[(size_t)u * GC + gi];
    acc += (double)(e * (log_bT[t[u*7] * GC + gi] + log_piT[(k & 3) * GC + gi]));
  }
  acc += __shfl_xor(acc, 1);
  acc += __shfl_xor(acc, 2);
  acc += __shfl_xor(acc, 4);
  __shared__ double sd[64];
  if (i == 0) sd[(tid >> 7)*16 + g] = acc;
  __syncthreads();
  if (tid < 16) {
    double s = sd[tid] + sd[16 + tid] + sd[32 + tid] + sd[48 + tid];
    atomicAdd(&out[tid], (float)s);
  }
}

extern "C" void kernel_launch(void* const* d_in, const int* in_sizes, int n_in,
                              void* d_out, int out_size, void* d_ws, size_t ws_size,
                              hipStream_t stream) {
  const int*   t  = (const int*)d_in[0];
  // d_in[1] = t_limits (unused; tree shape is compile-time constant)
  const float* a  = (const float*)d_in[2];
  const float* b  = (const float*)d_in[3];
  const float* pi = (const float*)d_in[4];
  const float* sp = (const float*)d_in[5];
  float* out = (float*)d_out;

  char* w = (char*)d_ws;
  size_t off = 0;
  auto carve = [&](size_t bytes) -> void* {
    void* p = w + off;
    off += (bytes + 255) & ~(size_t)255;
    return p;
  };
  float* a_sp    = (float*)carve((size_t)16*8*8*4*4);
  float* log_a   = (float*)carve((size_t)16*8*8*4*4);
  float* sm_bT   = (float*)carve((size_t)256*GC*4);
  float* log_bT  = (float*)carve((size_t)256*GC*4);
  float* sm_piT  = (float*)carve((size_t)4*GC*4);
  float* log_piT = (float*)carve((size_t)4*GC*4);
  float* log_sp  = (float*)carve((size_t)16*4*4);
  float* beta    = (float*)carve((size_t)TSIZE*GC*4);
  float* numbeta = (float*)carve((size_t)SL*GC*4);
  float* eps     = (float*)carve((size_t)TSIZE*GC*4);

  setup_kernel<<<18, 256, 0, stream>>>(a, b, pi, sp, a_sp, log_a, sm_bT, log_bT,
                                       sm_piT, log_piT, log_sp, out);
  up_kernel<<<256, 512, 0, stream>>>(a_sp, sm_bT, sm_piT, t, beta, numbeta);
  top_kernel<<<16, 512, 0, stream>>>(a_sp, log_a, log_sp, sm_bT, log_bT, t,
                                     beta, numbeta, eps, out);
  down_kernel<<<256, 512, 0, stream>>>(a_sp, log_a, log_sp, log_bT, log_piT, t,
                                       numbeta, beta, eps, out);
}